// Round 4
// baseline (721.574 us; speedup 1.0000x reference)
//
#include <hip/hip_runtime.h>
#include <stdint.h>

// B=512, N=256, D=512.
// merged = ((softmax(msg A msg^T) col-sums) @ msg) @ Wv,  A = Wq Wk^T / sqrt(D)
// Pipeline: prep_a -> cast_msg_frag -> gemm_T3 -> attn_w2 -> final_merge_f
// Everything bf16 lives in FRAGMENT-MAJOR layout:
//   element(row, e) at ((rt*16 + ks)*64 + lane)*8 + j
//   rt = row>>4, ks = e>>5, lane = ((e>>3)&3)*16 + (row&15), j = e&7
// which is at once: MFMA A-frag layout (lane-contig 16B loads), B-frag panel
// layout, and contiguous per-16-row-tile (8192 shorts per rt).
// Fallback: round-1 fused kernel (ws >= 512KB only).

typedef __attribute__((ext_vector_type(8))) short short8;
typedef __attribute__((ext_vector_type(4))) float f32x4;

#define MFMA16(a,b,c) __builtin_amdgcn_mfma_f32_16x16x32_bf16((a),(b),(c),0,0,0)

__device__ __forceinline__ uint32_t f2bf(float f){
  uint32_t x = __float_as_uint(f);
  return (x + 0x7FFFu + ((x >> 16) & 1u)) >> 16;  // RNE
}
__device__ __forceinline__ float bf2f(uint32_t h){ return __uint_as_float(h << 16); }

// ---------------- kernel 1: A_swz = fragswz(bf16(norm * Wq @ Wk^T)) ----------------
__global__ __launch_bounds__(256) void prep_a(const float* __restrict__ wq,
                                              const float* __restrict__ wk,
                                              uint16_t* __restrict__ aswz){
  __shared__ float sQ[64][17];
  __shared__ float sK[64][17];
  const int tid = threadIdx.x;
  const int k0 = blockIdx.y * 64, c0 = blockIdx.x * 64;
  const int tx = tid & 15, ty = tid >> 4;
  const int lr = tid >> 2, lc = (tid & 3) * 4;
  float acc[4][4] = {{0.f}};

  for (int e0 = 0; e0 < 512; e0 += 16){
    __syncthreads();
    float4 q4 = *(const float4*)(wq + (size_t)(k0 + lr) * 512 + e0 + lc);
    float4 k4 = *(const float4*)(wk + (size_t)(c0 + lr) * 512 + e0 + lc);
    sQ[lr][lc+0] = q4.x; sQ[lr][lc+1] = q4.y; sQ[lr][lc+2] = q4.z; sQ[lr][lc+3] = q4.w;
    sK[lr][lc+0] = k4.x; sK[lr][lc+1] = k4.y; sK[lr][lc+2] = k4.z; sK[lr][lc+3] = k4.w;
    __syncthreads();
    #pragma unroll
    for (int e = 0; e < 16; e++){
      float qv[4], kv[4];
      #pragma unroll
      for (int i = 0; i < 4; i++) qv[i] = sQ[ty + 16*i][e];
      #pragma unroll
      for (int j = 0; j < 4; j++) kv[j] = sK[tx + 16*j][e];
      #pragma unroll
      for (int i = 0; i < 4; i++)
        #pragma unroll
        for (int j = 0; j < 4; j++) acc[i][j] += qv[i] * kv[j];
    }
  }
  const float norm = 0.04419417382415922f;  // 1/sqrt(512)
  #pragma unroll
  for (int i = 0; i < 4; i++){
    #pragma unroll
    for (int j = 0; j < 4; j++){
      int k = k0 + ty + 16*i, c = c0 + tx + 16*j;     // A[k][c], k = contraction
      int ks = k >> 5, q = (k >> 3) & 3, jj = k & 7, ct = c >> 4;
      int lane = q*16 + (c & 15);
      aswz[((size_t)((ct*16 + ks)*64 + lane))*8 + jj] = (uint16_t)f2bf(acc[i][j] * norm);
    }
  }
}

// ---------------- kernel 2: msgbf = bf16(msg) in fragment-major ----------------
// wave handles one 16-row tile rt; per ks: 16 rows x 32 e-cols (16 full cache
// lines read exactly once), write lane-contiguous 1KB.
__global__ __launch_bounds__(256) void cast_msg_frag(const float* __restrict__ msg,
                                                     uint16_t* __restrict__ mf){
  const int tid = threadIdx.x, w = tid >> 6, lane = tid & 63;
  const int l15 = lane & 15, q = lane >> 4;
  const int rt = blockIdx.x * 4 + w;
  const float* rowp = msg + (size_t)(rt*16 + l15) * 512;
  uint16_t* dst = mf + (size_t)rt * 8192 + lane * 8;
  #pragma unroll
  for (int ks = 0; ks < 16; ks++){
    const int col0 = ks*32 + q*8;
    float4 a = *(const float4*)(rowp + col0);
    float4 b = *(const float4*)(rowp + col0 + 4);
    uint4 pk;
    pk.x = f2bf(a.x) | (f2bf(a.y) << 16);
    pk.y = f2bf(a.z) | (f2bf(a.w) << 16);
    pk.z = f2bf(b.x) | (f2bf(b.y) << 16);
    pk.w = f2bf(b.z) | (f2bf(b.w) << 16);
    *(uint4*)(dst + ks*512) = pk;
  }
}

// ---------------- kernel 3: T = msgbf @ A  (frag-major in, frag-major out) ----------------
// Block: 4 waves x 32 rows = 128 rows, all 512 cols. A-frags: lane-contiguous
// 16B loads, no cvt. B (A_swz) staged per 32KB chunk into LDS. Epilogue:
// C-layout -> sE -> frag-major coalesced dwordx4 stores (chunk cg == ks group).
__global__ __launch_bounds__(256,2) void gemm_T3(const uint16_t* __restrict__ mf,
                                                 const uint16_t* __restrict__ aswz,
                                                 uint16_t* __restrict__ TF){
  __shared__ __align__(16) uint16_t sB[16384];      // 32 KB chunk
  __shared__ __align__(16) uint16_t sE[4][32][40];  // per-wave epilogue transpose
  const int tid = threadIdx.x, w = tid >> 6, lane = tid & 63;
  const int l15 = lane & 15, q = lane >> 4;
  const int rt0 = blockIdx.x * 8 + w * 2;           // wave's two row-tiles

  short8 aLo[16], aHi[16];
  {
    const short8* A0 = (const short8*)(mf + (size_t)rt0 * 8192) + lane;
    const short8* A1 = (const short8*)(mf + (size_t)(rt0+1) * 8192) + lane;
    #pragma unroll
    for (int ks = 0; ks < 16; ks++){ aLo[ks] = A0[ks*64]; aHi[ks] = A1[ks*64]; }
  }

  #pragma unroll 1
  for (int cg = 0; cg < 16; cg++){
    __syncthreads();
    {
      const uint4* gsrc = (const uint4*)(aswz + (size_t)cg * 16384);
      uint4* ldst = (uint4*)sB;
      #pragma unroll
      for (int p = 0; p < 8; p++) ldst[p*256 + tid] = gsrc[p*256 + tid];
    }
    __syncthreads();

    f32x4 a0 = {0.f,0.f,0.f,0.f}, a1 = {0.f,0.f,0.f,0.f};
    f32x4 a2 = {0.f,0.f,0.f,0.f}, a3 = {0.f,0.f,0.f,0.f};
    #pragma unroll
    for (int ks = 0; ks < 16; ks++){
      short8 b0 = *(const short8*)(sB + (ks*64 + lane)*8);
      short8 b1 = *(const short8*)(sB + 8192 + (ks*64 + lane)*8);
      a0 = MFMA16(aLo[ks], b0, a0);
      a1 = MFMA16(aLo[ks], b1, a1);
      a2 = MFMA16(aHi[ks], b0, a2);
      a3 = MFMA16(aHi[ks], b1, a3);
    }

    // C layout: row_local = q*4+r, col e_local = l15 (a0/a2) or 16+l15 (a1/a3)
    #pragma unroll
    for (int r = 0; r < 4; r++){
      sE[w][q*4 + r][l15]           = (uint16_t)f2bf(a0[r]);
      sE[w][q*4 + r][16 + l15]      = (uint16_t)f2bf(a1[r]);
      sE[w][16 + q*4 + r][l15]      = (uint16_t)f2bf(a2[r]);
      sE[w][16 + q*4 + r][16 + l15] = (uint16_t)f2bf(a3[r]);
    }
    // frag-major store: chunk cg == ks-group cg; lane L holds row l15, e_local q*8..+7
    // same-wave RAW through LDS (compiler inserts lgkmcnt wait)
    uint4 v0 = *(const uint4*)&sE[w][l15][q*8];
    uint4 v1 = *(const uint4*)&sE[w][16 + l15][q*8];
    *(uint4*)(TF + (size_t)rt0 * 8192 + cg*512 + lane*8)     = v0;
    *(uint4*)(TF + (size_t)(rt0+1) * 8192 + cg*512 + lane*8) = v1;
  }
}

// ---------------- kernel 4: S = T_b @ msgbf_b^T, softmax rows, column sums ----------------
// grid = 1024 (b, n-half of 128 rows), 512 threads = 8 waves x 16 rows.
// aT: lane-contiguous frag loads; panels: straight 64KB contiguous LDS copies.
__global__ __launch_bounds__(512,2) void attn_w2(const uint16_t* __restrict__ TF,
                                                 const uint16_t* __restrict__ mf,
                                                 float* __restrict__ w4){
  __shared__ __align__(16) uint16_t sP[32768];   // 64 KB panel (4 m-tiles, frag-major)
  __shared__ float sW[8][256];
  const int tid = threadIdx.x, w = tid >> 6, lane = tid & 63;
  const int l15 = lane & 15, q = lane >> 4;
  const int b = blockIdx.x >> 1, nh = blockIdx.x & 1;
  const int rt_a = b*16 + nh*8 + w;              // wave's n-row tile

  short8 aT[16];
  {
    const short8* A0 = (const short8*)(TF + (size_t)rt_a * 8192) + lane;
    #pragma unroll
    for (int ks = 0; ks < 16; ks++) aT[ks] = A0[ks*64];
  }

  f32x4 acc[16];
  #pragma unroll
  for (int t = 0; t < 16; t++) acc[t] = (f32x4){0.f,0.f,0.f,0.f};

  for (int mp = 0; mp < 4; mp++){
    __syncthreads();
    {
      const uint4* src = (const uint4*)(mf + ((size_t)b*16 + mp*4) * 8192);
      uint4* dst = (uint4*)sP;
      #pragma unroll
      for (int it = 0; it < 8; it++) dst[it*512 + tid] = src[it*512 + tid];
    }
    __syncthreads();
    #pragma unroll
    for (int ks = 0; ks < 16; ks++){
      short8 b0 = *(const short8*)(sP + (      ks)*512 + lane*8);
      short8 b1 = *(const short8*)(sP + (16 + ks)*512 + lane*8);
      short8 b2 = *(const short8*)(sP + (32 + ks)*512 + lane*8);
      short8 b3 = *(const short8*)(sP + (48 + ks)*512 + lane*8);
      acc[mp*4+0] = MFMA16(aT[ks], b0, acc[mp*4+0]);
      acc[mp*4+1] = MFMA16(aT[ks], b1, acc[mp*4+1]);
      acc[mp*4+2] = MFMA16(aT[ks], b2, acc[mp*4+2]);
      acc[mp*4+3] = MFMA16(aT[ks], b3, acc[mp*4+3]);
    }
  }

  // softmax per row (row n = nh*128 + w*16 + q*4+r, col m = t*16 + l15), col sums
  float mx[4], inv[4];
  #pragma unroll
  for (int r = 0; r < 4; r++){
    float m_ = acc[0][r];
    #pragma unroll
    for (int t = 1; t < 16; t++) m_ = fmaxf(m_, acc[t][r]);
    m_ = fmaxf(m_, __shfl_xor(m_, 1));
    m_ = fmaxf(m_, __shfl_xor(m_, 2));
    m_ = fmaxf(m_, __shfl_xor(m_, 4));
    m_ = fmaxf(m_, __shfl_xor(m_, 8));
    mx[r] = m_;
  }
  #pragma unroll
  for (int t = 0; t < 16; t++){
    #pragma unroll
    for (int r = 0; r < 4; r++) acc[t][r] = __expf(acc[t][r] - mx[r]);
  }
  #pragma unroll
  for (int r = 0; r < 4; r++){
    float s_ = 0.f;
    #pragma unroll
    for (int t = 0; t < 16; t++) s_ += acc[t][r];
    s_ += __shfl_xor(s_, 1);
    s_ += __shfl_xor(s_, 2);
    s_ += __shfl_xor(s_, 4);
    s_ += __shfl_xor(s_, 8);
    inv[r] = 1.f / s_;
  }
  #pragma unroll
  for (int t = 0; t < 16; t++){
    float wc = acc[t][0]*inv[0] + acc[t][1]*inv[1] + acc[t][2]*inv[2] + acc[t][3]*inv[3];
    wc += __shfl_xor(wc, 16);
    wc += __shfl_xor(wc, 32);
    if (lane < 16) sW[w][t*16 + lane] = wc;
  }
  __syncthreads();
  if (tid < 256){
    float s = 0.f;
    #pragma unroll
    for (int ww = 0; ww < 8; ww++) s += sW[ww][tid];
    w4[(size_t)b*512 + nh*256 + tid] = s;
  }
}

// ---------------- kernel 5: u = w^T msgbf_b (frag-major) ; out_b = u @ Wv ----------------
__global__ __launch_bounds__(256) void final_merge_f(const uint16_t* __restrict__ mf,
                                                     const float* __restrict__ w4,
                                                     const float* __restrict__ wvm,
                                                     float* __restrict__ out){
  __shared__ float sWm[256];
  __shared__ float sPart[16][516];
  __shared__ float sU[512];
  const int tid = threadIdx.x, b = blockIdx.x;
  sWm[tid] = w4[(size_t)b*512 + tid] + w4[(size_t)b*512 + 256 + tid];
  __syncthreads();
  const int l15 = tid & 15, g = tid >> 4;
  const uint4* base = (const uint4*)(mf + (size_t)b * 16 * 8192);
  #pragma unroll
  for (int s = 0; s < 4; s++){
    const int kq = g + 16*s;              // = ks*4 + qq;  e = kq*8 + j
    const int ks = kq >> 2, qq = kq & 3;
    float u8[8] = {0.f,0.f,0.f,0.f,0.f,0.f,0.f,0.f};
    #pragma unroll 4
    for (int mt = 0; mt < 16; mt++){
      uint4 v = base[(mt*16 + ks)*64 + qq*16 + l15];
      float wm = sWm[mt*16 + l15];        // m = mt*16 + l15
      u8[0] += wm * bf2f(v.x & 0xFFFFu); u8[1] += wm * bf2f(v.x >> 16);
      u8[2] += wm * bf2f(v.y & 0xFFFFu); u8[3] += wm * bf2f(v.y >> 16);
      u8[4] += wm * bf2f(v.z & 0xFFFFu); u8[5] += wm * bf2f(v.z >> 16);
      u8[6] += wm * bf2f(v.w & 0xFFFFu); u8[7] += wm * bf2f(v.w >> 16);
    }
    #pragma unroll
    for (int j = 0; j < 8; j++) sPart[l15][kq*8 + j] = u8[j];
  }
  __syncthreads();
  {
    float u0 = 0.f, u1 = 0.f;
    #pragma unroll
    for (int l = 0; l < 16; l++){ u0 += sPart[l][2*tid]; u1 += sPart[l][2*tid+1]; }
    sU[2*tid] = u0; sU[2*tid+1] = u1;
  }
  __syncthreads();
  const int e0 = tid * 2;
  float o0 = 0.f, o1 = 0.f;
  #pragma unroll 4
  for (int d = 0; d < 512; d++){
    float ud = sU[d];
    float2 wv2 = *(const float2*)(wvm + (size_t)d*512 + e0);
    o0 += ud * wv2.x; o1 += ud * wv2.y;
  }
  out[(size_t)b*512 + e0]     = o0;
  out[(size_t)b*512 + e0 + 1] = o1;
}

// ================= fallback: round-1 fused per-batch kernel =================
__device__ __forceinline__ void stage64(const float* __restrict__ src, uint16_t* dst, int tid){
  #pragma unroll 4
  for (int it = 0; it < 32; it++){
    int idx = it*256 + tid;
    int row = idx >> 7;
    int c4  = idx & 127;
    const float4 v = *(const float4*)(src + row*512 + c4*4);
    uint2 pk;
    pk.x = f2bf(v.x) | (f2bf(v.y) << 16);
    pk.y = f2bf(v.z) | (f2bf(v.w) << 16);
    *(uint2*)(dst + row*520 + c4*4) = pk;
  }
}

__global__ __launch_bounds__(256,1) void fused_attn(const float* __restrict__ msg,
                                                    const uint16_t* __restrict__ aswz,
                                                    const float* __restrict__ wvm,
                                                    float* __restrict__ out)
{
  __shared__ uint16_t sT[64*520];
  __shared__ uint16_t sStage[64*520];
  __shared__ float sW4[4][256];

  const int tid  = threadIdx.x;
  const int b    = blockIdx.x;
  const int lane = tid & 63;
  const int w    = tid >> 6;
  const int l15  = lane & 15;
  const int q    = lane >> 4;
  const float* mbp = msg + (size_t)b * (256*512);
  const short8* Ag = (const short8*)aswz;

  ((float*)sW4)[tid]       = 0.f;
  ((float*)sW4)[tid + 256] = 0.f;
  ((float*)sW4)[tid + 512] = 0.f;
  ((float*)sW4)[tid + 768] = 0.f;

  #pragma unroll 1
  for (int nc = 0; nc < 4; nc++){
    __syncthreads();
    stage64(mbp + nc*64*512, sStage, tid);
    __syncthreads();

    short8 aF[16];
    {
      const uint16_t* abase = sStage + (w*16 + l15)*520 + q*8;
      #pragma unroll
      for (int ks = 0; ks < 16; ks++) aF[ks] = *(const short8*)(abase + ks*32);
    }
    uint16_t* trow = sT + (w*16 + q*4)*520 + l15;
    for (int ct = 0; ct < 32; ct += 2){
      f32x4 a0 = {0.f,0.f,0.f,0.f}, a1 = {0.f,0.f,0.f,0.f};
      #pragma unroll
      for (int ks = 0; ks < 16; ks++){
        short8 b0 = Ag[(ct*16      + ks)*64 + lane];
        short8 b1 = Ag[(ct*16 + 16 + ks)*64 + lane];
        a0 = MFMA16(aF[ks], b0, a0);
        a1 = MFMA16(aF[ks], b1, a1);
      }
      #pragma unroll
      for (int r = 0; r < 4; r++){
        trow[r*520 + ct*16]      = (uint16_t)f2bf(a0[r]);
        trow[r*520 + ct*16 + 16] = (uint16_t)f2bf(a1[r]);
      }
    }

    f32x4 accS[16];
    #pragma unroll
    for (int t = 0; t < 16; t++) accS[t] = (f32x4){0.f,0.f,0.f,0.f};
    short8 aT[16];
    {
      const uint16_t* tbase = sT + (w*16 + l15)*520 + q*8;
      #pragma unroll
      for (int ks = 0; ks < 16; ks++) aT[ks] = *(const short8*)(tbase + ks*32);
    }
    #pragma unroll
    for (int mp = 0; mp < 4; mp++){
      __syncthreads();
      stage64(mbp + mp*64*512, sStage, tid);
      __syncthreads();
      const uint16_t* b0p = sStage + (     l15)*520 + q*8;
      const uint16_t* b1p = sStage + (16 + l15)*520 + q*8;
      const uint16_t* b2p = sStage + (32 + l15)*520 + q*8;
      const uint16_t* b3p = sStage + (48 + l15)*520 + q*8;
      #pragma unroll
      for (int ks = 0; ks < 16; ks++){
        short8 bb0 = *(const short8*)(b0p + ks*32);
        short8 bb1 = *(const short8*)(b1p + ks*32);
        short8 bb2 = *(const short8*)(b2p + ks*32);
        short8 bb3 = *(const short8*)(b3p + ks*32);
        accS[mp*4+0] = MFMA16(aT[ks], bb0, accS[mp*4+0]);
        accS[mp*4+1] = MFMA16(aT[ks], bb1, accS[mp*4+1]);
        accS[mp*4+2] = MFMA16(aT[ks], bb2, accS[mp*4+2]);
        accS[mp*4+3] = MFMA16(aT[ks], bb3, accS[mp*4+3]);
      }
    }

    float mx[4], inv[4];
    #pragma unroll
    for (int r = 0; r < 4; r++){
      float m_ = accS[0][r];
      #pragma unroll
      for (int t = 1; t < 16; t++) m_ = fmaxf(m_, accS[t][r]);
      m_ = fmaxf(m_, __shfl_xor(m_, 1));
      m_ = fmaxf(m_, __shfl_xor(m_, 2));
      m_ = fmaxf(m_, __shfl_xor(m_, 4));
      m_ = fmaxf(m_, __shfl_xor(m_, 8));
      mx[r] = m_;
    }
    #pragma unroll
    for (int t = 0; t < 16; t++){
      #pragma unroll
      for (int r = 0; r < 4; r++) accS[t][r] = __expf(accS[t][r] - mx[r]);
    }
    #pragma unroll
    for (int r = 0; r < 4; r++){
      float s_ = 0.f;
      #pragma unroll
      for (int t = 0; t < 16; t++) s_ += accS[t][r];
      s_ += __shfl_xor(s_, 1);
      s_ += __shfl_xor(s_, 2);
      s_ += __shfl_xor(s_, 4);
      s_ += __shfl_xor(s_, 8);
      inv[r] = 1.f / s_;
    }
    #pragma unroll
    for (int t = 0; t < 16; t++){
      float wc = accS[t][0]*inv[0] + accS[t][1]*inv[1] + accS[t][2]*inv[2] + accS[t][3]*inv[3];
      wc += __shfl_xor(wc, 16);
      wc += __shfl_xor(wc, 32);
      if (lane < 16) sW4[w][t*16 + lane] += wc;
    }
  }

  __syncthreads();
  {
    float wt = sW4[0][tid] + sW4[1][tid] + sW4[2][tid] + sW4[3][tid];
    sW4[0][tid] = wt;
  }
  __syncthreads();
  float u0 = 0.f, u1 = 0.f;
  for (int m = 0; m < 256; m++){
    float ww = sW4[0][m];
    u0 += ww * mbp[m*512 + tid];
    u1 += ww * mbp[m*512 + tid + 256];
  }
  float* sU = (float*)sStage;
  sU[tid] = u0; sU[tid + 256] = u1;
  __syncthreads();
  float o0 = 0.f, o1 = 0.f;
  for (int d = 0; d < 512; d++){
    float ud = sU[d];
    o0 += ud * wvm[(size_t)d*512 + tid];
    o1 += ud * wvm[(size_t)d*512 + tid + 256];
  }
  out[(size_t)b*512 + tid]       = o0;
  out[(size_t)b*512 + tid + 256] = o1;
}

extern "C" void kernel_launch(void* const* d_in, const int* in_sizes, int n_in,
                              void* d_out, int out_size, void* d_ws, size_t ws_size,
                              hipStream_t stream) {
  const float* msg = (const float*)d_in[0];
  const float* wq  = (const float*)d_in[1];
  const float* wk  = (const float*)d_in[2];
  const float* wv  = (const float*)d_in[3];

  const size_t SZ_A = 524288;            // A_swz bf16 512x512
  const size_t SZ_M = 134217728;         // msgbf frag-major
  const size_t SZ_T = 134217728;         // T frag-major
  const size_t SZ_W = 1048576;           // w slots fp32
  const size_t REQ  = SZ_A + SZ_M + SZ_T + SZ_W;

  uint16_t* aswz = (uint16_t*)d_ws;
  prep_a<<<dim3(8,8), 256, 0, stream>>>(wq, wk, aswz);

  if (ws_size >= REQ){
    uint16_t* mf = (uint16_t*)((char*)d_ws + SZ_A);
    uint16_t* TF = (uint16_t*)((char*)d_ws + SZ_A + SZ_M);
    float*    w4 = (float*)   ((char*)d_ws + SZ_A + SZ_M + SZ_T);
    cast_msg_frag<<<2048, 256, 0, stream>>>(msg, mf);
    gemm_T3      <<<1024, 256, 0, stream>>>(mf, aswz, TF);
    attn_w2      <<<1024, 512, 0, stream>>>(TF, mf, w4);
    final_merge_f<<<512, 256, 0, stream>>>(mf, w4, wv, (float*)d_out);
  } else {
    fused_attn<<<512, 256, 0, stream>>>(msg, aswz, wv, (float*)d_out);
  }
}